// Round 10
// baseline (155.031 us; speedup 1.0000x reference)
//
#include <hip/hip_runtime.h>
#include <math.h>

#define NFFT 1024
#define HOP 256
#define NFREQ 513
#define TFRAMES 1024
#define NT_TILE 8           /* 8 OWNED frames per block (+3 redundant next-group frames) */
#define LOUT  262400        /* (1024 + 256*1023) - 512 */

__device__ __forceinline__ float2 cadd(float2 a, float2 b){ return make_float2(a.x+b.x, a.y+b.y); }
__device__ __forceinline__ float2 csub(float2 a, float2 b){ return make_float2(a.x-b.x, a.y-b.y); }
__device__ __forceinline__ float2 muli(float2 a){ return make_float2(-a.y, a.x); }   // * i
__device__ __forceinline__ float2 cmul(float2 a, float2 b){
    return make_float2(a.x*b.x - a.y*b.y, a.x*b.y + a.y*b.x);
}

// inverse-sign (e^{+2pi i/8}) radix-8 DFT on 8 named registers — no arrays, no spill
__device__ __forceinline__ void radix8_inv(float2& v0, float2& v1, float2& v2, float2& v3,
                                           float2& v4, float2& v5, float2& v6, float2& v7) {
    const float C = 0.70710678118654752f;
    float2 a0 = cadd(v0, v4), a1 = csub(v0, v4);
    float2 a2 = cadd(v2, v6), a3 = csub(v2, v6);
    float2 b0 = cadd(v1, v5), b1 = csub(v1, v5);
    float2 b2 = cadd(v3, v7), b3 = csub(v3, v7);
    float2 E0 = cadd(a0, a2), E2 = csub(a0, a2);
    float2 E1 = cadd(a1, muli(a3)), E3 = csub(a1, muli(a3));
    float2 O0 = cadd(b0, b2), O2 = csub(b0, b2);
    float2 O1 = cadd(b1, muli(b3)), O3 = csub(b1, muli(b3));
    float2 T1 = make_float2(C*(O1.x - O1.y),  C*(O1.x + O1.y));   // O1 * w8
    float2 T2 = muli(O2);                                          // O2 * w8^2
    float2 T3 = make_float2(-C*(O3.x + O3.y), C*(O3.x - O3.y));    // O3 * w8^3
    v0 = cadd(E0, O0); v4 = csub(E0, O0);
    v1 = cadd(E1, T1); v5 = csub(E1, T1);
    v2 = cadd(E2, T2); v6 = csub(E2, T2);
    v3 = cadd(E3, T3); v7 = csub(E3, T3);
}

// phase-1 storage position of natural index n (0..511), XOR-swizzled within 64-blocks
__device__ __forceinline__ int zpos(int n) {
    int blk = n >> 6;
    return blk * 64 + ((n & 63) ^ ((9 * blk) & 63));
}

// full 512-point FFT (3 radix-8 stages) on frame fr, wave-private, register twiddles
__device__ __forceinline__ void fft_frame(float2* Zc, int fr, int lane6) {
    const float A512 = 0.012271846303085130f;   // 2*pi/512
    const int fx = fr << 1;
    // stage 1 (stride 64)
    {
        const int j = lane6, jx = lane6 ^ fx, zb = fr << 9;
        float2 v0 = Zc[zb +       (jx ^  0)];
        float2 v1 = Zc[zb +  64 + (jx ^  9)];
        float2 v2 = Zc[zb + 128 + (jx ^ 18)];
        float2 v3 = Zc[zb + 192 + (jx ^ 27)];
        float2 v4 = Zc[zb + 256 + (jx ^ 36)];
        float2 v5 = Zc[zb + 320 + (jx ^ 45)];
        float2 v6 = Zc[zb + 384 + (jx ^ 54)];
        float2 v7 = Zc[zb + 448 + (jx ^ 63)];
        radix8_inv(v0, v1, v2, v3, v4, v5, v6, v7);
        float swf, cwf;
        __sincosf((float)j * A512, &swf, &cwf);
        float2 w1 = make_float2(cwf, swf);
        float2 w2 = cmul(w1, w1);
        float2 w3 = cmul(w2, w1);
        float2 w4 = cmul(w2, w2);
        float2 w5 = cmul(w3, w2);
        float2 w6 = cmul(w3, w3);
        float2 w7 = cmul(w4, w3);
        Zc[zb +       (jx ^  0)] = v0;
        Zc[zb +  64 + (jx ^  9)] = cmul(v1, w1);
        Zc[zb + 128 + (jx ^ 18)] = cmul(v2, w2);
        Zc[zb + 192 + (jx ^ 27)] = cmul(v3, w3);
        Zc[zb + 256 + (jx ^ 36)] = cmul(v4, w4);
        Zc[zb + 320 + (jx ^ 45)] = cmul(v5, w5);
        Zc[zb + 384 + (jx ^ 54)] = cmul(v6, w6);
        Zc[zb + 448 + (jx ^ 63)] = cmul(v7, w7);
    }
    // stage 2 (stride 8 within 64-blocks)
    {
        const int b = lane6 >> 3, jp = lane6 & 7;
        const int sw = ((9 * b) & 63) ^ fx, bb = (fr << 9) + 64 * b;
        float2 v0 = Zc[bb + ((jp     ) ^ sw)];
        float2 v1 = Zc[bb + ((jp +  8) ^ sw)];
        float2 v2 = Zc[bb + ((jp + 16) ^ sw)];
        float2 v3 = Zc[bb + ((jp + 24) ^ sw)];
        float2 v4 = Zc[bb + ((jp + 32) ^ sw)];
        float2 v5 = Zc[bb + ((jp + 40) ^ sw)];
        float2 v6 = Zc[bb + ((jp + 48) ^ sw)];
        float2 v7 = Zc[bb + ((jp + 56) ^ sw)];
        radix8_inv(v0, v1, v2, v3, v4, v5, v6, v7);
        float swf, cwf;
        __sincosf((float)jp * 0.098174770424681039f /* 2pi/64 */, &swf, &cwf);
        float2 w1 = make_float2(cwf, swf);
        float2 w2 = cmul(w1, w1);
        float2 w3 = cmul(w2, w1);
        float2 w4 = cmul(w2, w2);
        float2 w5 = cmul(w3, w2);
        float2 w6 = cmul(w3, w3);
        float2 w7 = cmul(w4, w3);
        Zc[bb + ((jp     ) ^ sw)] = v0;
        Zc[bb + ((jp +  8) ^ sw)] = cmul(v1, w1);
        Zc[bb + ((jp + 16) ^ sw)] = cmul(v2, w2);
        Zc[bb + ((jp + 24) ^ sw)] = cmul(v3, w3);
        Zc[bb + ((jp + 32) ^ sw)] = cmul(v4, w4);
        Zc[bb + ((jp + 40) ^ sw)] = cmul(v5, w5);
        Zc[bb + ((jp + 48) ^ sw)] = cmul(v6, w6);
        Zc[bb + ((jp + 56) ^ sw)] = cmul(v7, w7);
    }
    // stage 3 (contiguous groups of 8, no twiddle)
    {
        const int b = lane6 >> 3, g = lane6 & 7;
        const int sw = ((9 * b) & 63) ^ fx, bb = (fr << 9) + 64 * b, g8 = 8 * g;
        float2 v0 = Zc[bb + ((g8    ) ^ sw)];
        float2 v1 = Zc[bb + ((g8 + 1) ^ sw)];
        float2 v2 = Zc[bb + ((g8 + 2) ^ sw)];
        float2 v3 = Zc[bb + ((g8 + 3) ^ sw)];
        float2 v4 = Zc[bb + ((g8 + 4) ^ sw)];
        float2 v5 = Zc[bb + ((g8 + 5) ^ sw)];
        float2 v6 = Zc[bb + ((g8 + 6) ^ sw)];
        float2 v7 = Zc[bb + ((g8 + 7) ^ sw)];
        radix8_inv(v0, v1, v2, v3, v4, v5, v6, v7);
        Zc[bb + ((g8    ) ^ sw)] = v0;
        Zc[bb + ((g8 + 1) ^ sw)] = v1;
        Zc[bb + ((g8 + 2) ^ sw)] = v2;
        Zc[bb + ((g8 + 3) ^ sw)] = v3;
        Zc[bb + ((g8 + 4) ^ sw)] = v4;
        Zc[bb + ((g8 + 5) ^ sw)] = v5;
        Zc[bb + ((g8 + 6) ^ sw)] = v6;
        Zc[bb + ((g8 + 7) ^ sw)] = v7;
    }
}

// EXCLUSIVE-OWNERSHIP ISTFT: block g owns out samples [g*2048+768, g*2048+2816)
// (tile 0 additionally [512,768); exact disjoint cover of LOUT). To finalize its
// tail seam it computes 3 redundant FFTs of the next group's frames 8..10
// (waves 0-2, second pass). ZERO atomics, ZERO memset: every output element is
// plain-stored exactly once (one float4 per thread; every owned sample has
// exactly 4 taps for tiles<127). LDS: Zc[11][512] = 45056 B -> 3 blocks/CU.
__global__ __launch_bounds__(512, 4) void istft_kernel(const float2* __restrict__ x,
                                                       float* __restrict__ out) {
    __shared__ float2 Zc[11 * 512];   // 45056 B

    const int tid  = threadIdx.x;
    const int bc   = blockIdx.y;
    const int tile = blockIdx.x;
    const int t0   = tile * NT_TILE;

    const float HR = 0.99998117528260111f, HI = 0.00613588464915448f; // e^{+i pi/512}
    const float C8 = 0.92387953251128676f, S8 = 0.38268343236508977f; // pi/8
    const float A512 = 0.012271846303085130f;   // 2*pi/512

    // ---------- phase 1a: frames 0..7 (coalesced 8-frame chunks) ----------
    {
        const int kg = tid >> 3, tt = tid & 7;
        const int tg = t0 + tt;
        const long baseIn = (long)bc * ((long)NFREQ * TFRAMES);
        const int wbase = tt << 9;
        const int fxw = tt << 1;
        float twr, twi;   // 0.5 * e^{+2pi i kp/1024}
        __sincosf((float)kg * 0.0061359231515425649f /* pi/512 */, &twi, &twr);
        twr *= 0.5f; twi *= 0.5f;
        #pragma unroll
        for (int i = 0; i < 5; ++i) {
            int kp = kg + 64 * i;
            if (kp <= 256) {
                float2 A = x[baseIn + (long)kp * TFRAMES + tg];
                float2 B = x[baseIn + (long)(512 - kp) * TFRAMES + tg];
                if (kp == 0) { A.y = 0.f; B.y = 0.f; }  // c2r drops DC/Nyquist imag
                float d2r = A.x - B.x, d2i = A.y + B.y;
                float o2r = twr * d2r - twi * d2i, o2i = twr * d2i + twi * d2r;
                float s2r = 0.5f * (A.x + B.x), s2i = 0.5f * (A.y - B.y);
                Zc[wbase + (zpos(kp) ^ fxw)] = make_float2(s2r - o2i, s2i + o2r);
                if (kp >= 1 && kp <= 255)
                    Zc[wbase + (zpos(512 - kp) ^ fxw)] = make_float2(s2r + o2i, o2r - s2i);
            }
            float nr = twr * C8 - twi * S8;   // rotate +pi/8 (kp += 64)
            twi = twr * S8 + twi * C8; twr = nr;
        }
    }
    // ---------- phase 1b: redundant frames 8..10 (next group's 0..2) ----------
    if (tile != 127) {
        const int kg2 = tid >> 2, ft = tid & 3;
        const int f2 = 8 + ft;
        const int tg2 = t0 + f2;
        const long baseIn = (long)bc * ((long)NFREQ * TFRAMES);
        const int wb2 = f2 << 9;
        const int fx2 = f2 << 1;
        float t2r, t2i;
        __sincosf((float)kg2 * 0.0061359231515425649f, &t2i, &t2r);
        t2r *= 0.5f; t2i *= 0.5f;
        const float C4 = 0.70710678118654752f;
        #pragma unroll
        for (int i = 0; i < 3; ++i) {
            int kp = kg2 + 128 * i;
            if (ft < 3 && kp <= 256) {
                float2 A = x[baseIn + (long)kp * TFRAMES + tg2];
                float2 B = x[baseIn + (long)(512 - kp) * TFRAMES + tg2];
                if (kp == 0) { A.y = 0.f; B.y = 0.f; }
                float d2r = A.x - B.x, d2i = A.y + B.y;
                float o2r = t2r * d2r - t2i * d2i, o2i = t2r * d2i + t2i * d2r;
                float s2r = 0.5f * (A.x + B.x), s2i = 0.5f * (A.y - B.y);
                Zc[wb2 + (zpos(kp) ^ fx2)] = make_float2(s2r - o2i, s2i + o2r);
                if (kp >= 1 && kp <= 255)
                    Zc[wb2 + (zpos(512 - kp) ^ fx2)] = make_float2(s2r + o2i, o2r - s2i);
            }
            float nr = t2r * C4 - t2i * C4;   // rotate +pi/4 (kp += 128)
            t2i = t2r * C4 + t2i * C4; t2r = nr;
        }
    }
    __syncthreads();

    const int f     = tid >> 6;      // wave-private frame (0..7)
    const int lane6 = tid & 63;

    fft_frame(Zc, f, lane6);
    if (tile != 127 && f < 3) fft_frame(Zc, 8 + f, lane6);
    __syncthreads();

    // ---------- window + overlap-add: owned range, plain float4 stores ----------
    // pair indices pi0 = 384+2*tid, pi0+1 -> samples sl0=768+4*tid .. +3.
    // m0 = 384 + (pi0 & 127); pairs share hi/k2v/tlo (pi0 even => no carry).
    {
        const int pi0 = 384 + (tid << 1);
        const int sl0 = pi0 << 1;
        const int slh = sl0 >> 8;                // 3..10
        const int tlo = slh - 3;                 // 0..7
        const int m0  = 384 + (pi0 & 127);
        const int k0  = m0 & 7;                  // even
        const int hi  = ((m0 >> 3) & 7) << 3;
        const int k2v = m0 >> 6;                 // 6..7
        const int sw9  = (9 * k0) & 63;
        const int sw9b = sw9 + 9;                // (9*(k0+1))&63, no overflow
        float se0, ce0, se1, ce1;
        __sincosf((float)m0 * A512, &se0, &ce0);
        __sincosf((float)(m0 + 1) * A512, &se1, &ce1);
        float ae0 = 0.f, ao0 = 0.f, ae1 = 0.f, ao1 = 0.f;
        const int cb = (tlo << 9) + (k0 << 6);
        if (tile != 127) {
            // every owned sample has exactly 4 taps: static sign-permutation loop
            #pragma unroll
            for (int u = 0; u < 4; ++u) {
                const int rx = (tlo + u) << 1;
                const int hk = hi | (k2v - 2 * u);
                float2 zA = Zc[cb +      (u << 9) + ((hk ^ sw9 ) ^ rx)];
                float2 zB = Zc[cb + 64 + (u << 9) + ((hk ^ sw9b) ^ rx)];
                float cA = (u == 0) ? ce0 : (u == 1) ? se0 : (u == 2) ? -ce0 : -se0;
                float sA = (u == 0) ? se0 : (u == 1) ? -ce0 : (u == 2) ? -se0 : ce0;
                float cB = (u == 0) ? ce1 : (u == 1) ? se1 : (u == 2) ? -ce1 : -se1;
                float sB = (u == 0) ? se1 : (u == 1) ? -ce1 : (u == 2) ? -se1 : ce1;
                ae0 += zA.x * (1.f - cA);
                ao0 += zA.y * (1.f - (cA * HR - sA * HI));
                ae1 += zB.x * (1.f - cB);
                ao1 += zB.y * (1.f - (cB * HR - sB * HI));
            }
        } else {
            // last tile: no next group; taps tlo..7 (ntap wave-uniform: 4,4,4,4,4,3,2,1)
            const int ntap = (slh <= 7) ? 4 : (11 - slh);
            float ceA = ce0, seA = se0, ceB = ce1, seB = se1;
            #pragma unroll 4
            for (int u = 0; u < ntap; ++u) {
                const int rx = (tlo + u) << 1;
                const int hk = hi | (k2v - 2 * u);
                float2 zA = Zc[cb +      (u << 9) + ((hk ^ sw9 ) ^ rx)];
                float2 zB = Zc[cb + 64 + (u << 9) + ((hk ^ sw9b) ^ rx)];
                ae0 += zA.x * (1.f - ceA);
                ao0 += zA.y * (1.f - (ceA * HR - seA * HI));
                ae1 += zB.x * (1.f - ceB);
                ao1 += zB.y * (1.f - (ceB * HR - seB * HI));
                float nA = seA; seA = -ceA; ceA = nA;    // rotate -pi/2 (exact)
                float nB = seB; seB = -ceB; ceB = nB;
            }
        }
        const int o = bc * LOUT + (tile << 11) + 256 + (tid << 2);
        reinterpret_cast<float4*>(out)[o >> 2] =
            make_float4(ae0 * 0.015625f, ao0 * 0.015625f, ae1 * 0.015625f, ao1 * 0.015625f);
    }

    // ---------- tile 0 extra: out [0,256) = local samples [512,768), 3 taps ----------
    if (tile == 0 && tid < 128) {
        const int pi  = 256 + tid;               // sl = 2*pi in [512,768)
        const int k0e = pi & 7;
        const int hie = ((pi >> 3) & 7) << 3;
        const int k2e = pi >> 6;                 // 4..5
        const int sw9e = (9 * k0e) & 63;
        float see, cee;
        __sincosf((float)pi * A512, &see, &cee);
        float ae = 0.f, ao = 0.f;
        const int cbe = k0e << 6;                // tlo = 0
        #pragma unroll
        for (int u = 0; u < 3; ++u) {
            const int rx = u << 1;
            const int hk = hie | (k2e - 2 * u);
            float2 zz = Zc[cbe + (u << 9) + ((hk ^ sw9e) ^ rx)];
            ae += zz.x * (1.f - cee);
            ao += zz.y * (1.f - (cee * HR - see * HI));
            float nc = see; see = -cee; cee = nc;
        }
        const int o = bc * LOUT + ((pi - 256) << 1);
        reinterpret_cast<float2*>(out)[o >> 1] = make_float2(ae * 0.015625f, ao * 0.015625f);
    }
}

extern "C" void kernel_launch(void* const* d_in, const int* in_sizes, int n_in,
                              void* d_out, int out_size, void* d_ws, size_t ws_size,
                              hipStream_t stream) {
    const float2* x = (const float2*)d_in[0];
    float* out = (float*)d_out;
    (void)in_sizes; (void)n_in; (void)d_ws; (void)ws_size; (void)out_size;

    // NO memset: exclusive ownership writes every output element exactly once.
    dim3 grid(TFRAMES / NT_TILE, 64);   // 128 tiles x 64 (B*C) rows
    dim3 block(512);
    istft_kernel<<<grid, block, 0, stream>>>(x, out);
}

// Round 14
// 129.382 us; speedup vs baseline: 1.1982x; 1.1982x over previous
//
#include <hip/hip_runtime.h>
#include <math.h>

#define NFFT 1024
#define HOP 256
#define NFREQ 513
#define TFRAMES 1024
#define NT_TILE 8           /* 8 frames per block */
#define LOUT  262400        /* (1024 + 256*1023) - 512 */
#define NPAIR 1408          /* pairs per block: samples [0, 2816) */

__device__ __forceinline__ float2 cadd(float2 a, float2 b){ return make_float2(a.x+b.x, a.y+b.y); }
__device__ __forceinline__ float2 csub(float2 a, float2 b){ return make_float2(a.x-b.x, a.y-b.y); }
__device__ __forceinline__ float2 muli(float2 a){ return make_float2(-a.y, a.x); }   // * i
__device__ __forceinline__ float2 cmul(float2 a, float2 b){
    return make_float2(a.x*b.x - a.y*b.y, a.x*b.y + a.y*b.x);
}

// inverse-sign (e^{+2pi i/8}) radix-8 DFT on 8 named registers — no arrays, no spill
__device__ __forceinline__ void radix8_inv(float2& v0, float2& v1, float2& v2, float2& v3,
                                           float2& v4, float2& v5, float2& v6, float2& v7) {
    const float C = 0.70710678118654752f;
    float2 a0 = cadd(v0, v4), a1 = csub(v0, v4);
    float2 a2 = cadd(v2, v6), a3 = csub(v2, v6);
    float2 b0 = cadd(v1, v5), b1 = csub(v1, v5);
    float2 b2 = cadd(v3, v7), b3 = csub(v3, v7);
    float2 E0 = cadd(a0, a2), E2 = csub(a0, a2);
    float2 E1 = cadd(a1, muli(a3)), E3 = csub(a1, muli(a3));
    float2 O0 = cadd(b0, b2), O2 = csub(b0, b2);
    float2 O1 = cadd(b1, muli(b3)), O3 = csub(b1, muli(b3));
    float2 T1 = make_float2(C*(O1.x - O1.y),  C*(O1.x + O1.y));   // O1 * w8
    float2 T2 = muli(O2);                                          // O2 * w8^2
    float2 T3 = make_float2(-C*(O3.x + O3.y), C*(O3.x - O3.y));    // O3 * w8^3
    v0 = cadd(E0, O0); v4 = csub(E0, O0);
    v1 = cadd(E1, T1); v5 = csub(E1, T1);
    v2 = cadd(E2, T2); v6 = csub(E2, T2);
    v3 = cadd(E3, T3); v7 = csub(E3, T3);
}

// phase-1 storage position of natural index n (0..511), XOR-swizzled within 64-blocks
__device__ __forceinline__ int zpos(int n) {
    int blk = n >> 6;
    return blk * 64 + ((n & 63) ^ ((9 * blk) & 63));
}

// LDS: Zc only, 32768 B. NO twiddle table: every stage needs only POWERS of one
// per-thread base twiddle -> one __sincosf (TRANS pipe) + squaring chain in regs.
// launch_bounds stays (512,4): tighter bounds force spills (R1: +450 MB scratch).
__global__ __launch_bounds__(512, 4) void istft_kernel(const float2* __restrict__ x,
                                                       float* __restrict__ out) {
    __shared__ float2 Zc[8 * 512];    // 32768 B

    const int tid  = threadIdx.x;
    const int bc   = blockIdx.y;
    const int tile = blockIdx.x;
    const int t0   = tile * NT_TILE;
    const int S0   = t0 * HOP;

    // half-step rotation e^{+i pi/512} for odd bins / odd samples
    const float HR = 0.99998117528260111f, HI = 0.00613588464915448f;
    // pi/8 rotation for the phase-1 twiddle chain (kp steps of 64)
    const float C8 = 0.92387953251128676f, S8 = 0.38268343236508977f;
    const float A512 = 0.012271846303085130f;   // 2*pi/512

    // ---------- phase 1: global load + pack half-size spectrum ----------
    {
        const int kg = tid >> 3, tt = tid & 7;
        const int tg = t0 + tt;
        const long baseIn = (long)bc * ((long)NFREQ * TFRAMES);
        const int wbase = tt << 9;
        const int fxw = tt << 1;
        float twr, twi;   // 0.5 * e^{+2pi i kp/1024}, kp = kg initially (0.5 pack factor folded)
        __sincosf((float)kg * 0.0061359231515425649f /* pi/512 */, &twi, &twr);
        twr *= 0.5f; twi *= 0.5f;
        #pragma unroll
        for (int i = 0; i < 5; ++i) {
            int kp = kg + 64 * i;
            if (kp <= 256) {
                float2 A = x[baseIn + (long)kp * TFRAMES + tg];
                float2 B = x[baseIn + (long)(512 - kp) * TFRAMES + tg];
                if (kp == 0) { A.y = 0.f; B.y = 0.f; }  // c2r drops DC/Nyquist imag
                float d2r = A.x - B.x, d2i = A.y + B.y;
                float o2r = twr * d2r - twi * d2i, o2i = twr * d2i + twi * d2r;  // x0.5 folded
                float s2r = 0.5f * (A.x + B.x), s2i = 0.5f * (A.y - B.y);
                Zc[wbase + (zpos(kp) ^ fxw)] = make_float2(s2r - o2i, s2i + o2r);
                if (kp >= 1 && kp <= 255)
                    Zc[wbase + (zpos(512 - kp) ^ fxw)] = make_float2(s2r + o2i, o2r - s2i);
            }
            float nr = twr * C8 - twi * S8;   // rotate +pi/8 (kp += 64), preserves 0.5 scale
            twi = twr * S8 + twi * C8; twr = nr;
        }
    }
    __syncthreads();

    const int f     = tid >> 6;      // wave-private frame (0..7)
    const int lane6 = tid & 63;
    const int fbase = f << 9;
    const int fx    = f << 1;        // per-frame bank swizzle (replaces stride pad)

    // ---------- radix-8 DIF stage 1 (stride 64) — wave-private, no barriers ----------
    {
        const int j = lane6, jx = lane6 ^ fx, zb = fbase;
        float2 v0 = Zc[zb +       (jx ^  0)];
        float2 v1 = Zc[zb +  64 + (jx ^  9)];
        float2 v2 = Zc[zb + 128 + (jx ^ 18)];
        float2 v3 = Zc[zb + 192 + (jx ^ 27)];
        float2 v4 = Zc[zb + 256 + (jx ^ 36)];
        float2 v5 = Zc[zb + 320 + (jx ^ 45)];
        float2 v6 = Zc[zb + 384 + (jx ^ 54)];
        float2 v7 = Zc[zb + 448 + (jx ^ 63)];
        radix8_inv(v0, v1, v2, v3, v4, v5, v6, v7);
        // register twiddles: w = e^{+2pi i j/512}; powers by squaring (depth <= 3)
        float sw_, cw_;
        __sincosf((float)j * A512, &sw_, &cw_);
        float2 w1 = make_float2(cw_, sw_);
        float2 w2 = cmul(w1, w1);
        float2 w3 = cmul(w2, w1);
        float2 w4 = cmul(w2, w2);
        float2 w5 = cmul(w3, w2);
        float2 w6 = cmul(w3, w3);
        float2 w7 = cmul(w4, w3);
        Zc[zb +       (jx ^  0)] = v0;
        Zc[zb +  64 + (jx ^  9)] = cmul(v1, w1);
        Zc[zb + 128 + (jx ^ 18)] = cmul(v2, w2);
        Zc[zb + 192 + (jx ^ 27)] = cmul(v3, w3);
        Zc[zb + 256 + (jx ^ 36)] = cmul(v4, w4);
        Zc[zb + 320 + (jx ^ 45)] = cmul(v5, w5);
        Zc[zb + 384 + (jx ^ 54)] = cmul(v6, w6);
        Zc[zb + 448 + (jx ^ 63)] = cmul(v7, w7);
    }
    // ---------- stage 2 (stride 8 within 64-blocks) ----------
    {
        const int b = lane6 >> 3, jp = lane6 & 7;
        const int sw = ((9 * b) & 63) ^ fx, bb = fbase + 64 * b;
        float2 v0 = Zc[bb + ((jp     ) ^ sw)];
        float2 v1 = Zc[bb + ((jp +  8) ^ sw)];
        float2 v2 = Zc[bb + ((jp + 16) ^ sw)];
        float2 v3 = Zc[bb + ((jp + 24) ^ sw)];
        float2 v4 = Zc[bb + ((jp + 32) ^ sw)];
        float2 v5 = Zc[bb + ((jp + 40) ^ sw)];
        float2 v6 = Zc[bb + ((jp + 48) ^ sw)];
        float2 v7 = Zc[bb + ((jp + 56) ^ sw)];
        radix8_inv(v0, v1, v2, v3, v4, v5, v6, v7);
        // register twiddles: w = e^{+2pi i jp/64}
        float sw_, cw_;
        __sincosf((float)jp * 0.098174770424681039f /* 2pi/64 */, &sw_, &cw_);
        float2 w1 = make_float2(cw_, sw_);
        float2 w2 = cmul(w1, w1);
        float2 w3 = cmul(w2, w1);
        float2 w4 = cmul(w2, w2);
        float2 w5 = cmul(w3, w2);
        float2 w6 = cmul(w3, w3);
        float2 w7 = cmul(w4, w3);
        Zc[bb + ((jp     ) ^ sw)] = v0;
        Zc[bb + ((jp +  8) ^ sw)] = cmul(v1, w1);
        Zc[bb + ((jp + 16) ^ sw)] = cmul(v2, w2);
        Zc[bb + ((jp + 24) ^ sw)] = cmul(v3, w3);
        Zc[bb + ((jp + 32) ^ sw)] = cmul(v4, w4);
        Zc[bb + ((jp + 40) ^ sw)] = cmul(v5, w5);
        Zc[bb + ((jp + 48) ^ sw)] = cmul(v6, w6);
        Zc[bb + ((jp + 56) ^ sw)] = cmul(v7, w7);
    }
    // ---------- stage 3 (contiguous groups of 8, no twiddle) ----------
    {
        const int b = lane6 >> 3, g = lane6 & 7;
        const int sw = ((9 * b) & 63) ^ fx, bb = fbase + 64 * b, g8 = 8 * g;
        float2 v0 = Zc[bb + ((g8    ) ^ sw)];
        float2 v1 = Zc[bb + ((g8 + 1) ^ sw)];
        float2 v2 = Zc[bb + ((g8 + 2) ^ sw)];
        float2 v3 = Zc[bb + ((g8 + 3) ^ sw)];
        float2 v4 = Zc[bb + ((g8 + 4) ^ sw)];
        float2 v5 = Zc[bb + ((g8 + 5) ^ sw)];
        float2 v6 = Zc[bb + ((g8 + 6) ^ sw)];
        float2 v7 = Zc[bb + ((g8 + 7) ^ sw)];
        radix8_inv(v0, v1, v2, v3, v4, v5, v6, v7);
        Zc[bb + ((g8    ) ^ sw)] = v0;
        Zc[bb + ((g8 + 1) ^ sw)] = v1;
        Zc[bb + ((g8 + 2) ^ sw)] = v2;
        Zc[bb + ((g8 + 3) ^ sw)] = v3;
        Zc[bb + ((g8 + 4) ^ sw)] = v4;
        Zc[bb + ((g8 + 5) ^ sw)] = v5;
        Zc[bb + ((g8 + 6) ^ sw)] = v6;
        Zc[bb + ((g8 + 7) ^ sw)] = v7;
    }
    __syncthreads();

    // ---------- window + overlap-add: three exact-trip specialized loops ----------
    // r0 head (taps 1-4, wave-uniform), r1 interior (static 4 taps, no predicates),
    // r2 tail (taps 1-3, wave-uniform) REUSING r1's full setup: same m0 since
    // m0 = pi+512 - (tlo+4)*128 = pi - tlo*128. Quarter-turn taps (m -= 128 = -pi/2).

    // r0: pi = tid in [0,512), frames 0..slh
    {
        const int pi = tid;
        const int slh = pi >> 7;                 // 0..3, wave-uniform
        const int k0 = pi & 7;
        const int hi = ((pi >> 3) & 7) << 3;
        const int k2v = pi >> 6;
        const int sw9 = (9 * k0) & 63;
        float se, ce;
        __sincosf((float)pi * A512, &se, &ce);   // (cos, sin) of 2pi*pi/512
        float ae = 0.f, ao = 0.f;
        const int cb = k0 << 6;                  // tlo = 0
        #pragma unroll 4
        for (int u = 0; u <= slh; ++u) {
            int low = ((hi | (k2v - 2 * u)) ^ sw9) ^ (u << 1);
            float2 zz = Zc[cb + (u << 9) + low];
            float cou = ce * HR - se * HI;       // odd-sample window angle
            ae += zz.x * (1.f - ce);
            ao += zz.y * (1.f - cou);
            float nc = se; se = -ce; ce = nc;    // rotate -pi/2 (exact)
        }
        ae *= 0.015625f; ao *= 0.015625f;        // sqrt(1024)*0.5/512/2 folded
        int s = S0 + (pi << 1);
        int o = bc * LOUT + (s - 512);
        if (pi >= 384) {                         // sl in [768,1024): group-exclusive
            reinterpret_cast<float2*>(out)[o >> 1] = make_float2(ae, ao);
        } else if (s >= 512) {                   // head seam / head-trim boundary
            atomicAdd(&out[o],     ae);
            atomicAdd(&out[o + 1], ao);
        }
    }

    // r1 + r2 (shared setup)
    {
        const int pi = tid + 512;                // [512,1024)
        const int slh = pi >> 7;                 // 4..7
        const int tlo = slh - 3;                 // 1..4
        const int m0 = pi - (tlo << 7);          // in [384,512)
        const int k0 = m0 & 7;
        const int hi = ((m0 >> 3) & 7) << 3;
        const int k2v = m0 >> 6;
        const int sw9 = (9 * k0) & 63;
        float se0, ce0;
        __sincosf((float)m0 * A512, &se0, &ce0);
        const float ce = ce0, se = se0;
        const int cb = (tlo << 9) + (k0 << 6);

        // r1: always 4 taps, static sign permutations, no predicates
        {
            float ae = 0.f, ao = 0.f;
            #pragma unroll
            for (int u = 0; u < 4; ++u) {
                int low = ((hi | (k2v - 2 * u)) ^ sw9) ^ ((tlo + u) << 1);
                float2 zz = Zc[cb + (u << 9) + low];
                float cu = (u == 0) ? ce : (u == 1) ? se : (u == 2) ? -ce : -se;
                float su = (u == 0) ? se : (u == 1) ? -ce : (u == 2) ? -se : ce;
                float cou = cu * HR - su * HI;
                ae += zz.x * (1.f - cu);
                ao += zz.y * (1.f - cou);
            }
            ae *= 0.015625f; ao *= 0.015625f;
            int s = S0 + (pi << 1);
            reinterpret_cast<float2*>(out)[(bc * LOUT + (s - 512)) >> 1] = make_float2(ae, ao);
        }

        // r2: pi2 = pi + 512 in [1024,1408), frames tlo+4..7 (1-3 taps, wave-uniform)
        if (tid < 384) {
            const int ntap = 4 - tlo;            // 3,2,1
            float ce2 = ce, se2 = se;
            float ae = 0.f, ao = 0.f;
            const int cb2 = cb + (4 << 9);
            #pragma unroll 3
            for (int u = 0; u < ntap; ++u) {
                int low = ((hi | (k2v - 2 * u)) ^ sw9) ^ ((tlo + 4 + u) << 1);
                float2 zz = Zc[cb2 + (u << 9) + low];
                float cou = ce2 * HR - se2 * HI;
                ae += zz.x * (1.f - ce2);
                ao += zz.y * (1.f - cou);
                float nc = se2; se2 = -ce2; ce2 = nc;
            }
            ae *= 0.015625f; ao *= 0.015625f;
            int s = S0 + ((pi + 512) << 1);      // >= 2048, always >= 512
            int o = bc * LOUT + (s - 512);
            atomicAdd(&out[o],     ae);          // tail seam with next tile
            atomicAdd(&out[o + 1], ao);
        }
    }
}

extern "C" void kernel_launch(void* const* d_in, const int* in_sizes, int n_in,
                              void* d_out, int out_size, void* d_ws, size_t ws_size,
                              hipStream_t stream) {
    const float2* x = (const float2*)d_in[0];
    float* out = (float*)d_out;
    (void)in_sizes; (void)n_in; (void)d_ws; (void)ws_size;

    hipMemsetAsync(d_out, 0, (size_t)out_size * sizeof(float), stream);

    dim3 grid(TFRAMES / NT_TILE, 64);   // 128 tiles x 64 (B*C) rows
    dim3 block(512);
    istft_kernel<<<grid, block, 0, stream>>>(x, out);
}

// Round 15
// 125.090 us; speedup vs baseline: 1.2394x; 1.0343x over previous
//
#include <hip/hip_runtime.h>
#include <math.h>

#define NFFT 1024
#define HOP 256
#define NFREQ 513
#define TFRAMES 1024
#define NT_TILE 8           /* 8 frames per block */
#define LOUT  262400        /* (1024 + 256*1023) - 512 */
#define NPAIR 1408          /* pairs per block: samples [0, 2816) */

__device__ __forceinline__ float2 cadd(float2 a, float2 b){ return make_float2(a.x+b.x, a.y+b.y); }
__device__ __forceinline__ float2 csub(float2 a, float2 b){ return make_float2(a.x-b.x, a.y-b.y); }
__device__ __forceinline__ float2 muli(float2 a){ return make_float2(-a.y, a.x); }   // * i
__device__ __forceinline__ float2 cmul(float2 a, float2 b){
    return make_float2(a.x*b.x - a.y*b.y, a.x*b.y + a.y*b.x);
}

// inverse-sign (e^{+2pi i/8}) radix-8 DFT on 8 named registers — no arrays, no spill
__device__ __forceinline__ void radix8_inv(float2& v0, float2& v1, float2& v2, float2& v3,
                                           float2& v4, float2& v5, float2& v6, float2& v7) {
    const float C = 0.70710678118654752f;
    float2 a0 = cadd(v0, v4), a1 = csub(v0, v4);
    float2 a2 = cadd(v2, v6), a3 = csub(v2, v6);
    float2 b0 = cadd(v1, v5), b1 = csub(v1, v5);
    float2 b2 = cadd(v3, v7), b3 = csub(v3, v7);
    float2 E0 = cadd(a0, a2), E2 = csub(a0, a2);
    float2 E1 = cadd(a1, muli(a3)), E3 = csub(a1, muli(a3));
    float2 O0 = cadd(b0, b2), O2 = csub(b0, b2);
    float2 O1 = cadd(b1, muli(b3)), O3 = csub(b1, muli(b3));
    float2 T1 = make_float2(C*(O1.x - O1.y),  C*(O1.x + O1.y));   // O1 * w8
    float2 T2 = muli(O2);                                          // O2 * w8^2
    float2 T3 = make_float2(-C*(O3.x + O3.y), C*(O3.x - O3.y));    // O3 * w8^3
    v0 = cadd(E0, O0); v4 = csub(E0, O0);
    v1 = cadd(E1, T1); v5 = csub(E1, T1);
    v2 = cadd(E2, T2); v6 = csub(E2, T2);
    v3 = cadd(E3, T3); v7 = csub(E3, T3);
}

// phase-1 storage position of natural index n (0..511), XOR-swizzled within 64-blocks
__device__ __forceinline__ int zpos(int n) {
    int blk = n >> 6;
    return blk * 64 + ((n & 63) ^ ((9 * blk) & 63));
}

// Zero ONLY the output regions atomics land in: per bc, head [0,256) and seam
// stripes [g*2048+1536, g*2048+2304) for g=0..127 (exact cover of all atomic
// destinations; plain-stored regions are fully overwritten so need no zeroing).
// 25.2 MB instead of the 67 MB full-buffer memset.
#define GRAN_PER_BC 24640   /* float4 granules: 64 head + 128*192 stripe */
__global__ __launch_bounds__(256) void zero_seams(float* __restrict__ out) {
    int idx = blockIdx.x * 256 + threadIdx.x;
    if (idx >= 64 * GRAN_PER_BC) return;
    int bc = idx / GRAN_PER_BC;
    int r  = idx - bc * GRAN_PER_BC;
    int off;
    if (r < 64) {
        off = r << 2;                         // head [0,256)
    } else {
        int r2 = r - 64;
        int g  = r2 / 192;
        int w  = r2 - g * 192;
        off = g * 2048 + 1536 + (w << 2);     // stripe [1536,2304) of group g
    }
    *reinterpret_cast<float4*>(out + (long)bc * LOUT + off) = make_float4(0.f, 0.f, 0.f, 0.f);
}

// LDS: Zc only, 32768 B. NO twiddle table: every stage needs only POWERS of one
// per-thread base twiddle -> one __sincosf (TRANS pipe) + squaring chain in regs.
// launch_bounds stays (512,4): tighter bounds force spills (R1: +450 MB scratch).
__global__ __launch_bounds__(512, 4) void istft_kernel(const float2* __restrict__ x,
                                                       float* __restrict__ out) {
    __shared__ float2 Zc[8 * 512];    // 32768 B

    const int tid  = threadIdx.x;
    const int bc   = blockIdx.y;
    const int tile = blockIdx.x;
    const int t0   = tile * NT_TILE;
    const int S0   = t0 * HOP;

    // half-step rotation e^{+i pi/512} for odd bins / odd samples
    const float HR = 0.99998117528260111f, HI = 0.00613588464915448f;
    // pi/8 rotation for the phase-1 twiddle chain (kp steps of 64)
    const float C8 = 0.92387953251128676f, S8 = 0.38268343236508977f;
    const float A512 = 0.012271846303085130f;   // 2*pi/512

    // ---------- phase 1: global load + pack half-size spectrum ----------
    {
        const int kg = tid >> 3, tt = tid & 7;
        const int tg = t0 + tt;
        const long baseIn = (long)bc * ((long)NFREQ * TFRAMES);
        const int wbase = tt << 9;
        const int fxw = tt << 1;
        float twr, twi;   // 0.5 * e^{+2pi i kp/1024}, kp = kg initially (0.5 pack factor folded)
        __sincosf((float)kg * 0.0061359231515425649f /* pi/512 */, &twi, &twr);
        twr *= 0.5f; twi *= 0.5f;
        #pragma unroll
        for (int i = 0; i < 5; ++i) {
            int kp = kg + 64 * i;
            if (kp <= 256) {
                float2 A = x[baseIn + (long)kp * TFRAMES + tg];
                float2 B = x[baseIn + (long)(512 - kp) * TFRAMES + tg];
                if (kp == 0) { A.y = 0.f; B.y = 0.f; }  // c2r drops DC/Nyquist imag
                float d2r = A.x - B.x, d2i = A.y + B.y;
                float o2r = twr * d2r - twi * d2i, o2i = twr * d2i + twi * d2r;  // x0.5 folded
                float s2r = 0.5f * (A.x + B.x), s2i = 0.5f * (A.y - B.y);
                Zc[wbase + (zpos(kp) ^ fxw)] = make_float2(s2r - o2i, s2i + o2r);
                if (kp >= 1 && kp <= 255)
                    Zc[wbase + (zpos(512 - kp) ^ fxw)] = make_float2(s2r + o2i, o2r - s2i);
            }
            float nr = twr * C8 - twi * S8;   // rotate +pi/8 (kp += 64), preserves 0.5 scale
            twi = twr * S8 + twi * C8; twr = nr;
        }
    }
    __syncthreads();

    const int f     = tid >> 6;      // wave-private frame (0..7)
    const int lane6 = tid & 63;
    const int fbase = f << 9;
    const int fx    = f << 1;        // per-frame bank swizzle (replaces stride pad)

    // ---------- radix-8 DIF stage 1 (stride 64) — wave-private, no barriers ----------
    {
        const int j = lane6, jx = lane6 ^ fx, zb = fbase;
        float2 v0 = Zc[zb +       (jx ^  0)];
        float2 v1 = Zc[zb +  64 + (jx ^  9)];
        float2 v2 = Zc[zb + 128 + (jx ^ 18)];
        float2 v3 = Zc[zb + 192 + (jx ^ 27)];
        float2 v4 = Zc[zb + 256 + (jx ^ 36)];
        float2 v5 = Zc[zb + 320 + (jx ^ 45)];
        float2 v6 = Zc[zb + 384 + (jx ^ 54)];
        float2 v7 = Zc[zb + 448 + (jx ^ 63)];
        radix8_inv(v0, v1, v2, v3, v4, v5, v6, v7);
        // register twiddles: w = e^{+2pi i j/512}; powers by squaring (depth <= 3)
        float sw_, cw_;
        __sincosf((float)j * A512, &sw_, &cw_);
        float2 w1 = make_float2(cw_, sw_);
        float2 w2 = cmul(w1, w1);
        float2 w3 = cmul(w2, w1);
        float2 w4 = cmul(w2, w2);
        float2 w5 = cmul(w3, w2);
        float2 w6 = cmul(w3, w3);
        float2 w7 = cmul(w4, w3);
        Zc[zb +       (jx ^  0)] = v0;
        Zc[zb +  64 + (jx ^  9)] = cmul(v1, w1);
        Zc[zb + 128 + (jx ^ 18)] = cmul(v2, w2);
        Zc[zb + 192 + (jx ^ 27)] = cmul(v3, w3);
        Zc[zb + 256 + (jx ^ 36)] = cmul(v4, w4);
        Zc[zb + 320 + (jx ^ 45)] = cmul(v5, w5);
        Zc[zb + 384 + (jx ^ 54)] = cmul(v6, w6);
        Zc[zb + 448 + (jx ^ 63)] = cmul(v7, w7);
    }
    // ---------- stage 2 (stride 8 within 64-blocks) ----------
    {
        const int b = lane6 >> 3, jp = lane6 & 7;
        const int sw = ((9 * b) & 63) ^ fx, bb = fbase + 64 * b;
        float2 v0 = Zc[bb + ((jp     ) ^ sw)];
        float2 v1 = Zc[bb + ((jp +  8) ^ sw)];
        float2 v2 = Zc[bb + ((jp + 16) ^ sw)];
        float2 v3 = Zc[bb + ((jp + 24) ^ sw)];
        float2 v4 = Zc[bb + ((jp + 32) ^ sw)];
        float2 v5 = Zc[bb + ((jp + 40) ^ sw)];
        float2 v6 = Zc[bb + ((jp + 48) ^ sw)];
        float2 v7 = Zc[bb + ((jp + 56) ^ sw)];
        radix8_inv(v0, v1, v2, v3, v4, v5, v6, v7);
        // register twiddles: w = e^{+2pi i jp/64}
        float sw_, cw_;
        __sincosf((float)jp * 0.098174770424681039f /* 2pi/64 */, &sw_, &cw_);
        float2 w1 = make_float2(cw_, sw_);
        float2 w2 = cmul(w1, w1);
        float2 w3 = cmul(w2, w1);
        float2 w4 = cmul(w2, w2);
        float2 w5 = cmul(w3, w2);
        float2 w6 = cmul(w3, w3);
        float2 w7 = cmul(w4, w3);
        Zc[bb + ((jp     ) ^ sw)] = v0;
        Zc[bb + ((jp +  8) ^ sw)] = cmul(v1, w1);
        Zc[bb + ((jp + 16) ^ sw)] = cmul(v2, w2);
        Zc[bb + ((jp + 24) ^ sw)] = cmul(v3, w3);
        Zc[bb + ((jp + 32) ^ sw)] = cmul(v4, w4);
        Zc[bb + ((jp + 40) ^ sw)] = cmul(v5, w5);
        Zc[bb + ((jp + 48) ^ sw)] = cmul(v6, w6);
        Zc[bb + ((jp + 56) ^ sw)] = cmul(v7, w7);
    }
    // ---------- stage 3 (contiguous groups of 8, no twiddle) ----------
    {
        const int b = lane6 >> 3, g = lane6 & 7;
        const int sw = ((9 * b) & 63) ^ fx, bb = fbase + 64 * b, g8 = 8 * g;
        float2 v0 = Zc[bb + ((g8    ) ^ sw)];
        float2 v1 = Zc[bb + ((g8 + 1) ^ sw)];
        float2 v2 = Zc[bb + ((g8 + 2) ^ sw)];
        float2 v3 = Zc[bb + ((g8 + 3) ^ sw)];
        float2 v4 = Zc[bb + ((g8 + 4) ^ sw)];
        float2 v5 = Zc[bb + ((g8 + 5) ^ sw)];
        float2 v6 = Zc[bb + ((g8 + 6) ^ sw)];
        float2 v7 = Zc[bb + ((g8 + 7) ^ sw)];
        radix8_inv(v0, v1, v2, v3, v4, v5, v6, v7);
        Zc[bb + ((g8    ) ^ sw)] = v0;
        Zc[bb + ((g8 + 1) ^ sw)] = v1;
        Zc[bb + ((g8 + 2) ^ sw)] = v2;
        Zc[bb + ((g8 + 3) ^ sw)] = v3;
        Zc[bb + ((g8 + 4) ^ sw)] = v4;
        Zc[bb + ((g8 + 5) ^ sw)] = v5;
        Zc[bb + ((g8 + 6) ^ sw)] = v6;
        Zc[bb + ((g8 + 7) ^ sw)] = v7;
    }
    __syncthreads();

    // ---------- window + overlap-add: three exact-trip specialized loops ----------
    // r0 head (taps 1-4, wave-uniform), r1 interior (static 4 taps, no predicates),
    // r2 tail (taps 1-3, wave-uniform) REUSING r1's full setup: same m0 since
    // m0 = pi+512 - (tlo+4)*128 = pi - tlo*128. Quarter-turn taps (m -= 128 = -pi/2).

    // r0: pi = tid in [0,512), frames 0..slh
    {
        const int pi = tid;
        const int slh = pi >> 7;                 // 0..3, wave-uniform
        const int k0 = pi & 7;
        const int hi = ((pi >> 3) & 7) << 3;
        const int k2v = pi >> 6;
        const int sw9 = (9 * k0) & 63;
        float se, ce;
        __sincosf((float)pi * A512, &se, &ce);   // (cos, sin) of 2pi*pi/512
        float ae = 0.f, ao = 0.f;
        const int cb = k0 << 6;                  // tlo = 0
        #pragma unroll 4
        for (int u = 0; u <= slh; ++u) {
            int low = ((hi | (k2v - 2 * u)) ^ sw9) ^ (u << 1);
            float2 zz = Zc[cb + (u << 9) + low];
            float cou = ce * HR - se * HI;       // odd-sample window angle
            ae += zz.x * (1.f - ce);
            ao += zz.y * (1.f - cou);
            float nc = se; se = -ce; ce = nc;    // rotate -pi/2 (exact)
        }
        ae *= 0.015625f; ao *= 0.015625f;        // sqrt(1024)*0.5/512/2 folded
        int s = S0 + (pi << 1);
        int o = bc * LOUT + (s - 512);
        if (pi >= 384) {                         // sl in [768,1024): group-exclusive
            reinterpret_cast<float2*>(out)[o >> 1] = make_float2(ae, ao);
        } else if (s >= 512) {                   // head seam / head-trim boundary
            atomicAdd(&out[o],     ae);
            atomicAdd(&out[o + 1], ao);
        }
    }

    // r1 + r2 (shared setup)
    {
        const int pi = tid + 512;                // [512,1024)
        const int slh = pi >> 7;                 // 4..7
        const int tlo = slh - 3;                 // 1..4
        const int m0 = pi - (tlo << 7);          // in [384,512)
        const int k0 = m0 & 7;
        const int hi = ((m0 >> 3) & 7) << 3;
        const int k2v = m0 >> 6;
        const int sw9 = (9 * k0) & 63;
        float se0, ce0;
        __sincosf((float)m0 * A512, &se0, &ce0);
        const float ce = ce0, se = se0;
        const int cb = (tlo << 9) + (k0 << 6);

        // r1: always 4 taps, static sign permutations, no predicates
        {
            float ae = 0.f, ao = 0.f;
            #pragma unroll
            for (int u = 0; u < 4; ++u) {
                int low = ((hi | (k2v - 2 * u)) ^ sw9) ^ ((tlo + u) << 1);
                float2 zz = Zc[cb + (u << 9) + low];
                float cu = (u == 0) ? ce : (u == 1) ? se : (u == 2) ? -ce : -se;
                float su = (u == 0) ? se : (u == 1) ? -ce : (u == 2) ? -se : ce;
                float cou = cu * HR - su * HI;
                ae += zz.x * (1.f - cu);
                ao += zz.y * (1.f - cou);
            }
            ae *= 0.015625f; ao *= 0.015625f;
            int s = S0 + (pi << 1);
            reinterpret_cast<float2*>(out)[(bc * LOUT + (s - 512)) >> 1] = make_float2(ae, ao);
        }

        // r2: pi2 = pi + 512 in [1024,1408), frames tlo+4..7 (1-3 taps, wave-uniform)
        if (tid < 384) {
            const int ntap = 4 - tlo;            // 3,2,1
            float ce2 = ce, se2 = se;
            float ae = 0.f, ao = 0.f;
            const int cb2 = cb + (4 << 9);
            #pragma unroll 3
            for (int u = 0; u < ntap; ++u) {
                int low = ((hi | (k2v - 2 * u)) ^ sw9) ^ ((tlo + 4 + u) << 1);
                float2 zz = Zc[cb2 + (u << 9) + low];
                float cou = ce2 * HR - se2 * HI;
                ae += zz.x * (1.f - ce2);
                ao += zz.y * (1.f - cou);
                float nc = se2; se2 = -ce2; ce2 = nc;
            }
            ae *= 0.015625f; ao *= 0.015625f;
            int s = S0 + ((pi + 512) << 1);      // >= 2048, always >= 512
            int o = bc * LOUT + (s - 512);
            atomicAdd(&out[o],     ae);          // tail seam with next tile
            atomicAdd(&out[o + 1], ao);
        }
    }
}

extern "C" void kernel_launch(void* const* d_in, const int* in_sizes, int n_in,
                              void* d_out, int out_size, void* d_ws, size_t ws_size,
                              hipStream_t stream) {
    const float2* x = (const float2*)d_in[0];
    float* out = (float*)d_out;
    (void)in_sizes; (void)n_in; (void)d_ws; (void)ws_size; (void)out_size;

    // Stripe-zero only the atomic-landing regions (25.2 MB vs 67 MB full memset).
    {
        int total = 64 * GRAN_PER_BC;
        dim3 zgrid((total + 255) / 256);
        zero_seams<<<zgrid, dim3(256), 0, stream>>>(out);
    }

    dim3 grid(TFRAMES / NT_TILE, 64);   // 128 tiles x 64 (B*C) rows
    dim3 block(512);
    istft_kernel<<<grid, block, 0, stream>>>(x, out);
}

// Round 16
// 123.403 us; speedup vs baseline: 1.2563x; 1.0137x over previous
//
#include <hip/hip_runtime.h>
#include <math.h>

#define NFFT 1024
#define HOP 256
#define NFREQ 513
#define TFRAMES 1024
#define NT_TILE 8           /* 8 frames per block */
#define LOUT  262400        /* (1024 + 256*1023) - 512 */
#define NPAIR 1408          /* pairs per block: samples [0, 2816) */

__device__ __forceinline__ float2 cadd(float2 a, float2 b){ return make_float2(a.x+b.x, a.y+b.y); }
__device__ __forceinline__ float2 csub(float2 a, float2 b){ return make_float2(a.x-b.x, a.y-b.y); }
__device__ __forceinline__ float2 muli(float2 a){ return make_float2(-a.y, a.x); }   // * i
__device__ __forceinline__ float2 cmul(float2 a, float2 b){
    return make_float2(a.x*b.x - a.y*b.y, a.x*b.y + a.y*b.x);
}

// inverse-sign (e^{+2pi i/8}) radix-8 DFT on 8 named registers — no arrays, no spill
__device__ __forceinline__ void radix8_inv(float2& v0, float2& v1, float2& v2, float2& v3,
                                           float2& v4, float2& v5, float2& v6, float2& v7) {
    const float C = 0.70710678118654752f;
    float2 a0 = cadd(v0, v4), a1 = csub(v0, v4);
    float2 a2 = cadd(v2, v6), a3 = csub(v2, v6);
    float2 b0 = cadd(v1, v5), b1 = csub(v1, v5);
    float2 b2 = cadd(v3, v7), b3 = csub(v3, v7);
    float2 E0 = cadd(a0, a2), E2 = csub(a0, a2);
    float2 E1 = cadd(a1, muli(a3)), E3 = csub(a1, muli(a3));
    float2 O0 = cadd(b0, b2), O2 = csub(b0, b2);
    float2 O1 = cadd(b1, muli(b3)), O3 = csub(b1, muli(b3));
    float2 T1 = make_float2(C*(O1.x - O1.y),  C*(O1.x + O1.y));   // O1 * w8
    float2 T2 = muli(O2);                                          // O2 * w8^2
    float2 T3 = make_float2(-C*(O3.x + O3.y), C*(O3.x - O3.y));    // O3 * w8^3
    v0 = cadd(E0, O0); v4 = csub(E0, O0);
    v1 = cadd(E1, T1); v5 = csub(E1, T1);
    v2 = cadd(E2, T2); v6 = csub(E2, T2);
    v3 = cadd(E3, T3); v7 = csub(E3, T3);
}

// phase-1 storage position of natural index n (0..511), XOR-swizzled within 64-blocks
__device__ __forceinline__ int zpos(int n) {
    int blk = n >> 6;
    return blk * 64 + ((n & 63) ^ ((9 * blk) & 63));
}

// Zero ONLY the output regions atomics land in: per bc, head [0,256) and seam
// stripes [g*2048+1536, g*2048+2304) for g=0..127 (exact cover of all atomic
// destinations; plain-stored regions are fully overwritten so need no zeroing).
// 25.2 MB instead of the 67 MB full-buffer memset.  [R15: -4.3 us]
#define GRAN_PER_BC 24640   /* float4 granules: 64 head + 128*192 stripe */
__global__ __launch_bounds__(256) void zero_seams(float* __restrict__ out) {
    int idx = blockIdx.x * 256 + threadIdx.x;
    if (idx >= 64 * GRAN_PER_BC) return;
    int bc = idx / GRAN_PER_BC;
    int r  = idx - bc * GRAN_PER_BC;
    int off;
    if (r < 64) {
        off = r << 2;                         // head [0,256)
    } else {
        int r2 = r - 64;
        int g  = r2 / 192;
        int w  = r2 - g * 192;
        off = g * 2048 + 1536 + (w << 2);     // stripe [1536,2304) of group g
    }
    *reinterpret_cast<float4*>(out + (long)bc * LOUT + off) = make_float4(0.f, 0.f, 0.f, 0.f);
}

// LDS: Zc only, 32768 B. Register twiddles everywhere (no table).
// Phase 1: float4 loads (2 time-frames/thread), exact-trip 2-iteration loop,
// kp=256 handled by a 4-thread tail (Zc[pos(256)] = conj(x[256][tg])).
// launch_bounds stays (512,4): tighter bounds force spills (R1: +450 MB scratch).
__global__ __launch_bounds__(512, 4) void istft_kernel(const float2* __restrict__ x,
                                                       float* __restrict__ out) {
    __shared__ float2 Zc[8 * 512];    // 32768 B

    const int tid  = threadIdx.x;
    const int bc   = blockIdx.y;
    const int tile = blockIdx.x;
    const int t0   = tile * NT_TILE;
    const int S0   = t0 * HOP;

    // half-step rotation e^{+i pi/512} for odd bins / odd samples
    const float HR = 0.99998117528260111f, HI = 0.00613588464915448f;
    const float A512 = 0.012271846303085130f;   // 2*pi/512

    // ---------- phase 1: float4 global load + pack half-size spectrum ----------
    // Each thread: rows kg, kg+128 (and the mirror rows 512-kp), 2 time-frames
    // (tt2, tt2+1) via one float4 per row. kp in [0,255] always: no trip predicate.
    {
        const int kg  = tid >> 2;             // 0..127
        const int tt2 = (tid & 3) << 1;       // frames tt2, tt2+1 (even => 16B aligned)
        const int tg  = t0 + tt2;
        const long baseIn = (long)bc * ((long)NFREQ * TFRAMES);
        float twr, twi;   // 0.5 * e^{+2pi i kp/1024}, kp = kg initially (0.5 pack folded)
        __sincosf((float)kg * 0.0061359231515425649f /* pi/512 */, &twi, &twr);
        twr *= 0.5f; twi *= 0.5f;
        #pragma unroll
        for (int i = 0; i < 2; ++i) {
            const int kp = kg + 128 * i;      // 0..255 always
            float4 A2 = *reinterpret_cast<const float4*>(&x[baseIn + (long)kp * TFRAMES + tg]);
            float4 B2 = *reinterpret_cast<const float4*>(&x[baseIn + (long)(512 - kp) * TFRAMES + tg]);
            if (kp == 0) { A2.y = 0.f; A2.w = 0.f; B2.y = 0.f; B2.w = 0.f; }  // c2r DC imag
            const int zp = zpos(kp);
            const int zm = zpos((512 - kp) & 511);   // used only when kp >= 1
            #pragma unroll
            for (int s2 = 0; s2 < 2; ++s2) {
                const float Ax = s2 ? A2.z : A2.x, Ay = s2 ? A2.w : A2.y;
                const float Bx = s2 ? B2.z : B2.x, By = s2 ? B2.w : B2.y;
                const int fr = tt2 + s2;
                const int wbase = fr << 9, fxw = fr << 1;
                float d2r = Ax - Bx, d2i = Ay + By;
                float o2r = twr * d2r - twi * d2i, o2i = twr * d2i + twi * d2r;  // x0.5 folded
                float s2r = 0.5f * (Ax + Bx), s2i = 0.5f * (Ay - By);
                Zc[wbase + (zp ^ fxw)] = make_float2(s2r - o2i, s2i + o2r);
                if (kp >= 1)
                    Zc[wbase + (zm ^ fxw)] = make_float2(s2r + o2i, o2r - s2i);
            }
            // rotate +pi/4 (kp += 128), preserves the 0.5 scale
            const float C4 = 0.70710678118654752f;
            float nr = (twr - twi) * C4;
            twi = (twr + twi) * C4; twr = nr;
        }
        // kp = 256 (Nyquist-fold row): Zc[pos(256)] = conj(x[256][tg]) exactly
        if (tid < 4) {
            float4 A2 = *reinterpret_cast<const float4*>(&x[baseIn + (long)256 * TFRAMES + tg]);
            const int zp = zpos(256);
            Zc[( tt2      << 9) + (zp ^ ( tt2      << 1))] = make_float2(A2.x, -A2.y);
            Zc[((tt2 + 1) << 9) + (zp ^ ((tt2 + 1) << 1))] = make_float2(A2.z, -A2.w);
        }
    }
    __syncthreads();

    const int f     = tid >> 6;      // wave-private frame (0..7)
    const int lane6 = tid & 63;
    const int fbase = f << 9;
    const int fx    = f << 1;        // per-frame bank swizzle (replaces stride pad)

    // ---------- radix-8 DIF stage 1 (stride 64) — wave-private, no barriers ----------
    {
        const int j = lane6, jx = lane6 ^ fx, zb = fbase;
        float2 v0 = Zc[zb +       (jx ^  0)];
        float2 v1 = Zc[zb +  64 + (jx ^  9)];
        float2 v2 = Zc[zb + 128 + (jx ^ 18)];
        float2 v3 = Zc[zb + 192 + (jx ^ 27)];
        float2 v4 = Zc[zb + 256 + (jx ^ 36)];
        float2 v5 = Zc[zb + 320 + (jx ^ 45)];
        float2 v6 = Zc[zb + 384 + (jx ^ 54)];
        float2 v7 = Zc[zb + 448 + (jx ^ 63)];
        radix8_inv(v0, v1, v2, v3, v4, v5, v6, v7);
        // register twiddles: w = e^{+2pi i j/512}; powers by squaring (depth <= 3)
        float sw_, cw_;
        __sincosf((float)j * A512, &sw_, &cw_);
        float2 w1 = make_float2(cw_, sw_);
        float2 w2 = cmul(w1, w1);
        float2 w3 = cmul(w2, w1);
        float2 w4 = cmul(w2, w2);
        float2 w5 = cmul(w3, w2);
        float2 w6 = cmul(w3, w3);
        float2 w7 = cmul(w4, w3);
        Zc[zb +       (jx ^  0)] = v0;
        Zc[zb +  64 + (jx ^  9)] = cmul(v1, w1);
        Zc[zb + 128 + (jx ^ 18)] = cmul(v2, w2);
        Zc[zb + 192 + (jx ^ 27)] = cmul(v3, w3);
        Zc[zb + 256 + (jx ^ 36)] = cmul(v4, w4);
        Zc[zb + 320 + (jx ^ 45)] = cmul(v5, w5);
        Zc[zb + 384 + (jx ^ 54)] = cmul(v6, w6);
        Zc[zb + 448 + (jx ^ 63)] = cmul(v7, w7);
    }
    // ---------- stage 2 (stride 8 within 64-blocks) ----------
    {
        const int b = lane6 >> 3, jp = lane6 & 7;
        const int sw = ((9 * b) & 63) ^ fx, bb = fbase + 64 * b;
        float2 v0 = Zc[bb + ((jp     ) ^ sw)];
        float2 v1 = Zc[bb + ((jp +  8) ^ sw)];
        float2 v2 = Zc[bb + ((jp + 16) ^ sw)];
        float2 v3 = Zc[bb + ((jp + 24) ^ sw)];
        float2 v4 = Zc[bb + ((jp + 32) ^ sw)];
        float2 v5 = Zc[bb + ((jp + 40) ^ sw)];
        float2 v6 = Zc[bb + ((jp + 48) ^ sw)];
        float2 v7 = Zc[bb + ((jp + 56) ^ sw)];
        radix8_inv(v0, v1, v2, v3, v4, v5, v6, v7);
        // register twiddles: w = e^{+2pi i jp/64}
        float sw_, cw_;
        __sincosf((float)jp * 0.098174770424681039f /* 2pi/64 */, &sw_, &cw_);
        float2 w1 = make_float2(cw_, sw_);
        float2 w2 = cmul(w1, w1);
        float2 w3 = cmul(w2, w1);
        float2 w4 = cmul(w2, w2);
        float2 w5 = cmul(w3, w2);
        float2 w6 = cmul(w3, w3);
        float2 w7 = cmul(w4, w3);
        Zc[bb + ((jp     ) ^ sw)] = v0;
        Zc[bb + ((jp +  8) ^ sw)] = cmul(v1, w1);
        Zc[bb + ((jp + 16) ^ sw)] = cmul(v2, w2);
        Zc[bb + ((jp + 24) ^ sw)] = cmul(v3, w3);
        Zc[bb + ((jp + 32) ^ sw)] = cmul(v4, w4);
        Zc[bb + ((jp + 40) ^ sw)] = cmul(v5, w5);
        Zc[bb + ((jp + 48) ^ sw)] = cmul(v6, w6);
        Zc[bb + ((jp + 56) ^ sw)] = cmul(v7, w7);
    }
    // ---------- stage 3 (contiguous groups of 8, no twiddle) ----------
    {
        const int b = lane6 >> 3, g = lane6 & 7;
        const int sw = ((9 * b) & 63) ^ fx, bb = fbase + 64 * b, g8 = 8 * g;
        float2 v0 = Zc[bb + ((g8    ) ^ sw)];
        float2 v1 = Zc[bb + ((g8 + 1) ^ sw)];
        float2 v2 = Zc[bb + ((g8 + 2) ^ sw)];
        float2 v3 = Zc[bb + ((g8 + 3) ^ sw)];
        float2 v4 = Zc[bb + ((g8 + 4) ^ sw)];
        float2 v5 = Zc[bb + ((g8 + 5) ^ sw)];
        float2 v6 = Zc[bb + ((g8 + 6) ^ sw)];
        float2 v7 = Zc[bb + ((g8 + 7) ^ sw)];
        radix8_inv(v0, v1, v2, v3, v4, v5, v6, v7);
        Zc[bb + ((g8    ) ^ sw)] = v0;
        Zc[bb + ((g8 + 1) ^ sw)] = v1;
        Zc[bb + ((g8 + 2) ^ sw)] = v2;
        Zc[bb + ((g8 + 3) ^ sw)] = v3;
        Zc[bb + ((g8 + 4) ^ sw)] = v4;
        Zc[bb + ((g8 + 5) ^ sw)] = v5;
        Zc[bb + ((g8 + 6) ^ sw)] = v6;
        Zc[bb + ((g8 + 7) ^ sw)] = v7;
    }
    __syncthreads();

    // ---------- window + overlap-add: three exact-trip specialized loops ----------
    // r0 head (taps 1-4, wave-uniform), r1 interior (static 4 taps, no predicates),
    // r2 tail (taps 1-3, wave-uniform) REUSING r1's full setup: same m0 since
    // m0 = pi+512 - (tlo+4)*128 = pi - tlo*128. Quarter-turn taps (m -= 128 = -pi/2).

    // r0: pi = tid in [0,512), frames 0..slh
    {
        const int pi = tid;
        const int slh = pi >> 7;                 // 0..3, wave-uniform
        const int k0 = pi & 7;
        const int hi = ((pi >> 3) & 7) << 3;
        const int k2v = pi >> 6;
        const int sw9 = (9 * k0) & 63;
        float se, ce;
        __sincosf((float)pi * A512, &se, &ce);   // (cos, sin) of 2pi*pi/512
        float ae = 0.f, ao = 0.f;
        const int cb = k0 << 6;                  // tlo = 0
        #pragma unroll 4
        for (int u = 0; u <= slh; ++u) {
            int low = ((hi | (k2v - 2 * u)) ^ sw9) ^ (u << 1);
            float2 zz = Zc[cb + (u << 9) + low];
            float cou = ce * HR - se * HI;       // odd-sample window angle
            ae += zz.x * (1.f - ce);
            ao += zz.y * (1.f - cou);
            float nc = se; se = -ce; ce = nc;    // rotate -pi/2 (exact)
        }
        ae *= 0.015625f; ao *= 0.015625f;        // sqrt(1024)*0.5/512/2 folded
        int s = S0 + (pi << 1);
        int o = bc * LOUT + (s - 512);
        if (pi >= 384) {                         // sl in [768,1024): group-exclusive
            reinterpret_cast<float2*>(out)[o >> 1] = make_float2(ae, ao);
        } else if (s >= 512) {                   // head seam / head-trim boundary
            atomicAdd(&out[o],     ae);
            atomicAdd(&out[o + 1], ao);
        }
    }

    // r1 + r2 (shared setup)
    {
        const int pi = tid + 512;                // [512,1024)
        const int slh = pi >> 7;                 // 4..7
        const int tlo = slh - 3;                 // 1..4
        const int m0 = pi - (tlo << 7);          // in [384,512)
        const int k0 = m0 & 7;
        const int hi = ((m0 >> 3) & 7) << 3;
        const int k2v = m0 >> 6;
        const int sw9 = (9 * k0) & 63;
        float se0, ce0;
        __sincosf((float)m0 * A512, &se0, &ce0);
        const float ce = ce0, se = se0;
        const int cb = (tlo << 9) + (k0 << 6);

        // r1: always 4 taps, static sign permutations, no predicates
        {
            float ae = 0.f, ao = 0.f;
            #pragma unroll
            for (int u = 0; u < 4; ++u) {
                int low = ((hi | (k2v - 2 * u)) ^ sw9) ^ ((tlo + u) << 1);
                float2 zz = Zc[cb + (u << 9) + low];
                float cu = (u == 0) ? ce : (u == 1) ? se : (u == 2) ? -ce : -se;
                float su = (u == 0) ? se : (u == 1) ? -ce : (u == 2) ? -se : ce;
                float cou = cu * HR - su * HI;
                ae += zz.x * (1.f - cu);
                ao += zz.y * (1.f - cou);
            }
            ae *= 0.015625f; ao *= 0.015625f;
            int s = S0 + (pi << 1);
            reinterpret_cast<float2*>(out)[(bc * LOUT + (s - 512)) >> 1] = make_float2(ae, ao);
        }

        // r2: pi2 = pi + 512 in [1024,1408), frames tlo+4..7 (1-3 taps, wave-uniform)
        if (tid < 384) {
            const int ntap = 4 - tlo;            // 3,2,1
            float ce2 = ce, se2 = se;
            float ae = 0.f, ao = 0.f;
            const int cb2 = cb + (4 << 9);
            #pragma unroll 3
            for (int u = 0; u < ntap; ++u) {
                int low = ((hi | (k2v - 2 * u)) ^ sw9) ^ ((tlo + 4 + u) << 1);
                float2 zz = Zc[cb2 + (u << 9) + low];
                float cou = ce2 * HR - se2 * HI;
                ae += zz.x * (1.f - ce2);
                ao += zz.y * (1.f - cou);
                float nc = se2; se2 = -ce2; ce2 = nc;
            }
            ae *= 0.015625f; ao *= 0.015625f;
            int s = S0 + ((pi + 512) << 1);      // >= 2048, always >= 512
            int o = bc * LOUT + (s - 512);
            atomicAdd(&out[o],     ae);          // tail seam with next tile
            atomicAdd(&out[o + 1], ao);
        }
    }
}

extern "C" void kernel_launch(void* const* d_in, const int* in_sizes, int n_in,
                              void* d_out, int out_size, void* d_ws, size_t ws_size,
                              hipStream_t stream) {
    const float2* x = (const float2*)d_in[0];
    float* out = (float*)d_out;
    (void)in_sizes; (void)n_in; (void)d_ws; (void)ws_size; (void)out_size;

    // Stripe-zero only the atomic-landing regions (25.2 MB vs 67 MB full memset).
    {
        int total = 64 * GRAN_PER_BC;
        dim3 zgrid((total + 255) / 256);
        zero_seams<<<zgrid, dim3(256), 0, stream>>>(out);
    }

    dim3 grid(TFRAMES / NT_TILE, 64);   // 128 tiles x 64 (B*C) rows
    dim3 block(512);
    istft_kernel<<<grid, block, 0, stream>>>(x, out);
}